// Round 7
// baseline (188.673 us; speedup 1.0000x reference)
//
#include <hip/hip_runtime.h>

// ---------------------------------------------------------------------------
// DigitConvolutionalModel: x(32768,784) -> conv3x3(valid) -> 676
//   -> relu(@W1(676,300)+b1) -> relu(@W2(300,300)+b2) -> @W3(300,10)+b3
//
// R13 = R12 (all-async GEMM1, counted waits -- the verified win) + bf16 x
// staging: reg-load f32 -> cvt once -> swizzled ds_write bf16. Halves the
// dominant LDS-read term (A-frags 8 -> 4 ds_read_b128/chunk) and removes
// all f32->bf16 cvt from the MFMA loop.
//  - x bands of 128 cols, ring-2 (2 x 16KB bf16). Swizzle: 16B unit u of
//    row r stored at position u^(r&7); read with same XOR -> uniform banks.
//  - pf loads issued in last 2 chunks of previous band, AFTER that chunk's
//    STAGE_B -> barrier waits stay counted (VMW(2)/VMW(1)), pf in flight.
//  - B path / wave split (4m x (3|2)n) / tail / prep: R12 verbatim.
//  - LDS 72KB (B dbuf 40 + x 32), hbuf overlays after G1. 2 blocks/CU.
//  - Tripwires: WRITE_SIZE ~1.3MB (no spill), conflicts <= 1.5M.
// ---------------------------------------------------------------------------

typedef __bf16 bf16_t;
typedef __bf16 bf16x4 __attribute__((ext_vector_type(4)));
typedef __bf16 bf16x8 __attribute__((ext_vector_type(8)));
typedef float  f32x4  __attribute__((ext_vector_type(4)));

#define MFMA16(a, b, c) __builtin_amdgcn_mfma_f32_16x16x32_bf16((a), (b), (c), 0, 0, 0)

#define W1F_ELEMS (25 * 20 * 64 * 8)  // 256000  (K=800, N=320)
#define W2F_ELEMS (10 * 20 * 64 * 8)  // 102400  (K=320, N=320)
#define W3F_ELEMS (10 * 1 * 64 * 8)   // 5120    (K=320, N=16)

#define XSLOT 16384   // one bf16 x band: 64 rows x 256B (128 bf16 cols)
#define XBASE 40960   // Bbuf = 2 * 1280 frags * 16B

// ---------------------------------------------------------------------------
__global__ void prep_weights(const float* __restrict__ conv_w,
                             const float* __restrict__ W1,
                             const float* __restrict__ W2,
                             const float* __restrict__ W3,
                             bf16_t* __restrict__ W1f,
                             bf16_t* __restrict__ W2f,
                             bf16_t* __restrict__ W3f) {
    int idx = blockIdx.x * 256 + threadIdx.x;
    if (idx < 800 * 320) {
        int k = idx / 320;
        int n = idx - k * 320;
        float v = 0.0f;
        if (k < 784 && n < 300) {
            int py = k / 28;
            int px = k - py * 28;
#pragma unroll
            for (int ky = 0; ky < 3; ++ky) {
                int oy = py - ky;
                if (oy < 0 || oy > 25) continue;
#pragma unroll
                for (int kx = 0; kx < 3; ++kx) {
                    int ox = px - kx;
                    if (ox < 0 || ox > 25) continue;
                    v += conv_w[ky * 3 + kx] * W1[(oy * 26 + ox) * 300 + n];
                }
            }
        }
        int kc = k >> 5, quad = (k >> 3) & 3, j = k & 7;
        int nt = n >> 4, nin = n & 15;
        W1f[(((kc * 20 + nt) * 64 + quad * 16 + nin) << 3) + j] = (bf16_t)v;
    } else if (idx < 800 * 320 + 320 * 320) {
        int i2 = idx - 800 * 320;
        int k = i2 / 320;
        int n = i2 - k * 320;
        float v = (k < 300 && n < 300) ? W2[k * 300 + n] : 0.0f;
        int kc = k >> 5, quad = (k >> 3) & 3, j = k & 7;
        int nt = n >> 4, nin = n & 15;
        W2f[(((kc * 20 + nt) * 64 + quad * 16 + nin) << 3) + j] = (bf16_t)v;
    } else if (idx < 800 * 320 + 320 * 320 + 320 * 16) {
        int i3 = idx - (800 * 320 + 320 * 320);
        int k = i3 / 16;
        int n = i3 - k * 16;
        float v = (k < 300 && n < 10) ? W3[k * 10 + n] : 0.0f;
        int kc = k >> 5, quad = (k >> 3) & 3, j = k & 7;
        W3f[(((kc * 64) + quad * 16 + n) << 3) + j] = (bf16_t)v;
    }
}

// async global -> LDS, 16B/lane; LDS base wave-uniform, global addr per-lane.
__device__ __forceinline__ void stage16(const void* g, void* l) {
    __builtin_amdgcn_global_load_lds(
        (const __attribute__((address_space(1))) void*)g,
        (__attribute__((address_space(3))) void*)l, 16, 0, 0);
}

// ---------------------------------------------------------------------------
// Fused kernel. Block = 64 rows, 512 thr (8 waves). Wave w: 4 m-tiles x
// (3|2) n-tiles. B1 chunks LDS-dbuf'd (global_load_lds); x bf16 ring-2.
// ---------------------------------------------------------------------------
__global__ __launch_bounds__(512, 4) void fused_mlp(
    const float* __restrict__ x, const float* __restrict__ b1,
    const float* __restrict__ b2, const float* __restrict__ b3,
    const bf16x8* __restrict__ W1f, const bf16x8* __restrict__ W2f,
    const bf16x8* __restrict__ W3f, float* __restrict__ out) {
    __shared__ __align__(16) unsigned char smem[XBASE + 2 * XSLOT];  // 72 KB
    bf16x8* Bb   = (bf16x8*)smem;  // [2][1280] B1 chunk dbuf
    bf16x8* hbuf = (bf16x8*)smem;  // 40 KB overlay after G1
    bf16_t* hb   = (bf16_t*)smem;

    const int tid = threadIdx.x;
    const int w   = tid >> 6;
    const int l   = tid & 63;
    const int q   = l >> 4;
    const int l15 = l & 15;
    const int r7w = l15 & 7;
    const int r0  = blockIdx.x * 64;

    const bool t3    = (w < 4);
    const int  nt0   = t3 ? (w * 3) : (12 + (w - 4) * 2);
    const int  boff2 = t3 ? 128 : 64;

    // x-load / cvt maps: full bands: row = i*16+srow, f32-quad sc4 (0..31).
    const int srow = tid >> 5;
    const int sc4  = tid & 31;
    const int sr7  = srow & 7;
    // band-6 map: row = trow, f32-quad tc4 (only 0..3 valid = cols 768..783)
    const int trow = tid >> 3;
    const int tc4  = tid & 7;

    float4 pf[4];
    f32x4 acc[4][3];
#pragma unroll
    for (int m = 0; m < 4; ++m)
#pragma unroll
        for (int j = 0; j < 3; ++j) acc[m][j] = (f32x4){0.f, 0.f, 0.f, 0.f};

    // ---- B1 chunk staging (R12-verified): 20 groups of 64 frags ----------
#define STAGE_B(KC, BUF)                                                       \
    {                                                                          \
        const bf16x8* ws_ = W1f + (size_t)(KC)*1280 + l;                       \
        bf16x8* wd_ = Bb + (BUF)*1280;                                         \
        stage16(ws_ + w * 64, wd_ + w * 64);                                   \
        stage16(ws_ + (w + 8) * 64, wd_ + (w + 8) * 64);                       \
        if (w >= 4) stage16(ws_ + (w + 12) * 64, wd_ + (w + 12) * 64);         \
    }

    // ---- x VGPR loads (always issued AFTER a STAGE_B so waits stay counted)
#define LOADX(BAND, I)                                                         \
    pf[I] = *(const float4*)(x + (size_t)(r0 + (I)*16 + srow) * 784 +          \
                             (BAND)*128 + sc4 * 4);
#define LOADX_B6()                                                             \
    if (tc4 < 4)                                                               \
        pf[0] = *(const float4*)(x + (size_t)(r0 + trow) * 784 + 768 + tc4 * 4);

    // ---- cvt f32->bf16 + swizzled ds_write (unit u of row r at u^(r&7)) --
#define CVT_FULL(XW)                                                           \
    {                                                                          \
        const int pos_ = ((((sc4 >> 1) ^ sr7) << 4) + (sc4 & 1) * 8);          \
        _Pragma("unroll")                                                      \
        for (int i_ = 0; i_ < 4; ++i_) {                                       \
            bf16x4 v_;                                                         \
            v_[0] = (bf16_t)pf[i_].x; v_[1] = (bf16_t)pf[i_].y;                \
            v_[2] = (bf16_t)pf[i_].z; v_[3] = (bf16_t)pf[i_].w;                \
            *(bf16x4*)((XW) + (i_ * 16 + srow) * 256 + pos_) = v_;             \
        }                                                                      \
    }
#define CVT_B6(XW)                                                             \
    if (tc4 < 4) {                                                             \
        bf16x4 v_;                                                             \
        v_[0] = (bf16_t)pf[0].x; v_[1] = (bf16_t)pf[0].y;                      \
        v_[2] = (bf16_t)pf[0].z; v_[3] = (bf16_t)pf[0].w;                      \
        *(bf16x4*)((XW) + trow * 256 +                                         \
                   ((((tc4 >> 1) ^ (trow & 7)) << 4) + (tc4 & 1) * 8)) = v_;   \
    }

    // ---- one K=32 chunk: 4 bf16 A reads (swizzled, shared u across m) +
    // 3 B reads (contiguous 1KB) + 12|8 MFMA. No cvt.
#define G1CHUNK16(SLOT, KCL, BUF)                                              \
    {                                                                          \
        const unsigned char* sp_ =                                             \
            (SLOT) + l15 * 256 + (((((KCL)*4) + q) ^ r7w) << 4);               \
        bf16x8 a0 = *(const bf16x8*)(sp_);                                     \
        bf16x8 a1 = *(const bf16x8*)(sp_ + 4096);                              \
        bf16x8 a2 = *(const bf16x8*)(sp_ + 8192);                              \
        bf16x8 a3 = *(const bf16x8*)(sp_ + 12288);                             \
        const bf16x8* bb_ = Bb + (BUF)*1280 + nt0 * 64 + l;                    \
        bf16x8 b0 = bb_[0], b1v = bb_[64], b2v = bb_[boff2];                   \
        acc[0][0] = MFMA16(a0, b0, acc[0][0]);                                 \
        acc[1][0] = MFMA16(a1, b0, acc[1][0]);                                 \
        acc[2][0] = MFMA16(a2, b0, acc[2][0]);                                 \
        acc[3][0] = MFMA16(a3, b0, acc[3][0]);                                 \
        acc[0][1] = MFMA16(a0, b1v, acc[0][1]);                                \
        acc[1][1] = MFMA16(a1, b1v, acc[1][1]);                                \
        acc[2][1] = MFMA16(a2, b1v, acc[2][1]);                                \
        acc[3][1] = MFMA16(a3, b1v, acc[3][1]);                                \
        if (t3) {                                                              \
            acc[0][2] = MFMA16(a0, b2v, acc[0][2]);                            \
            acc[1][2] = MFMA16(a1, b2v, acc[1][2]);                            \
            acc[2][2] = MFMA16(a2, b2v, acc[2][2]);                            \
            acc[3][2] = MFMA16(a3, b2v, acc[3][2]);                            \
        }                                                                      \
    }

#define VMW(N) asm volatile("s_waitcnt vmcnt(" #N ") lgkmcnt(0)" ::: "memory")
#define BARRIER()                         \
    __builtin_amdgcn_s_barrier();         \
    __builtin_amdgcn_sched_barrier(0)

    // ---------------- GEMM1: 7 bands (6 x 128 cols + 1 x 32), 25 chunks ----
    // prologue: B(0) staged; band 0 loaded+cvt'd; band-1 pf in flight.
    STAGE_B(0, 0)
    LOADX(0, 0) LOADX(0, 1) LOADX(0, 2) LOADX(0, 3)
    { unsigned char* xw = smem + XBASE; CVT_FULL(xw) }  // cvt waits pf (drains B0 too; one-time)
    LOADX(1, 0) LOADX(1, 1) LOADX(1, 2) LOADX(1, 3)
    VMW(4);  // B(0) + slot0 writes done; band-1 pf stays in flight
    BARRIER();

    for (int b = 0; b <= 3; ++b) {
        const int k0 = 4 * b;
        unsigned char* xs = smem + XBASE + (b & 1) * XSLOT;
        unsigned char* xw = smem + XBASE + ((b + 1) & 1) * XSLOT;
        // chunk k0: cvt band b+1 (pf) after compute; publish at barrier
        STAGE_B(k0 + 1, 1)
        G1CHUNK16(xs, 0, 0)
        CVT_FULL(xw)
        VMW(0); BARRIER();
        // chunk k0+1
        STAGE_B(k0 + 2, 0)
        G1CHUNK16(xs, 1, 1)
        VMW(0); BARRIER();
        // chunk k0+2: first half of band b+2 pf (after STAGE_B -> counted)
        STAGE_B(k0 + 3, 1)
        LOADX(b + 2, 0) LOADX(b + 2, 1)
        G1CHUNK16(xs, 2, 0)
        VMW(2); BARRIER();
        // chunk k0+3: second half of band b+2 pf
        STAGE_B(k0 + 4, 0)
        LOADX(b + 2, 2) LOADX(b + 2, 3)
        G1CHUNK16(xs, 3, 1)
        VMW(2); BARRIER();
    }
    // band 4 (chunks 16-19): pf -> band 6 (single quad) at chunk 19
    {
        unsigned char* xs = smem + XBASE;          // slot 0
        unsigned char* xw = smem + XBASE + XSLOT;  // slot 1
        STAGE_B(17, 1) G1CHUNK16(xs, 0, 0) CVT_FULL(xw) VMW(0); BARRIER();
        STAGE_B(18, 0) G1CHUNK16(xs, 1, 1) VMW(0); BARRIER();
        STAGE_B(19, 1) G1CHUNK16(xs, 2, 0) VMW(0); BARRIER();
        STAGE_B(20, 0) LOADX_B6() G1CHUNK16(xs, 3, 1) VMW(1); BARRIER();
    }
    // band 5 (chunks 20-23): cvt band 6 into slot 0
    {
        unsigned char* xs = smem + XBASE + XSLOT;  // slot 1
        unsigned char* xw = smem + XBASE;          // slot 0
        STAGE_B(21, 1) G1CHUNK16(xs, 0, 0) CVT_B6(xw) VMW(0); BARRIER();
        STAGE_B(22, 0) G1CHUNK16(xs, 1, 1) VMW(0); BARRIER();
        STAGE_B(23, 1) G1CHUNK16(xs, 2, 0) VMW(0); BARRIER();
        STAGE_B(24, 0) G1CHUNK16(xs, 3, 1) VMW(0); BARRIER();
    }
    // band 6 (chunk 24): units 0-1 real (cols 768-783), 2-3 stale x zero W1f
    {
        unsigned char* xs = smem + XBASE;  // slot 0
        G1CHUNK16(xs, 0, 0)
        asm volatile("s_waitcnt lgkmcnt(0)" ::: "memory");
        BARRIER();  // all Bbuf/x reads done before hbuf overlay
    }

    // ---------------- h1 = relu(C1+b1) -> hbuf (A-frag order) --------------
#define HSTORE(J, BIAS)                                                        \
    {                                                                          \
        int n = (nt0 + (J)) * 16 + l15;                                        \
        float bias = (n < 300) ? (BIAS)[n] : 0.0f;                             \
        int kh = n >> 5, quad = (n >> 3) & 3, jj = n & 7;                      \
        _Pragma("unroll")                                                      \
        for (int mt = 0; mt < 4; ++mt)                                         \
            _Pragma("unroll")                                                  \
            for (int r = 0; r < 4; ++r) {                                      \
                float v = acc[mt][(J)][r] + bias;                              \
                v = v > 0.f ? v : 0.f;                                         \
                hb[(((kh * 4 + mt) * 64 + quad * 16 + q * 4 + r) << 3) + jj] = \
                    (bf16_t)v;                                                 \
            }                                                                  \
    }

    HSTORE(0, b1)
    HSTORE(1, b1)
    if (t3) HSTORE(2, b1)
    asm volatile("s_waitcnt lgkmcnt(0)" ::: "memory");
    BARRIER();  // h1 visible

    // ---------------- GEMM2: barrier-free; W2f frags from global (L2) ------
#pragma unroll
    for (int m = 0; m < 4; ++m)
#pragma unroll
        for (int j = 0; j < 3; ++j) acc[m][j] = (f32x4){0.f, 0.f, 0.f, 0.f};

    const bf16x8* bB2 = W2f + nt0 * 64 + l;

#define G2CHUNK(KC2)                                                           \
    {                                                                          \
        bf16x8 a0 = hbuf[((KC2)*4 + 0) * 64 + l];                              \
        bf16x8 a1 = hbuf[((KC2)*4 + 1) * 64 + l];                              \
        bf16x8 a2 = hbuf[((KC2)*4 + 2) * 64 + l];                              \
        bf16x8 a3 = hbuf[((KC2)*4 + 3) * 64 + l];                              \
        const bf16x8* bp = bB2 + (KC2)*1280;                                   \
        bf16x8 b0 = bp[0], b1v = bp[64], b2v = bp[boff2];                      \
        acc[0][0] = MFMA16(a0, b0, acc[0][0]);                                 \
        acc[1][0] = MFMA16(a1, b0, acc[1][0]);                                 \
        acc[2][0] = MFMA16(a2, b0, acc[2][0]);                                 \
        acc[3][0] = MFMA16(a3, b0, acc[3][0]);                                 \
        acc[0][1] = MFMA16(a0, b1v, acc[0][1]);                                \
        acc[1][1] = MFMA16(a1, b1v, acc[1][1]);                                \
        acc[2][1] = MFMA16(a2, b1v, acc[2][1]);                                \
        acc[3][1] = MFMA16(a3, b1v, acc[3][1]);                                \
        if (t3) {                                                              \
            acc[0][2] = MFMA16(a0, b2v, acc[0][2]);                            \
            acc[1][2] = MFMA16(a1, b2v, acc[1][2]);                            \
            acc[2][2] = MFMA16(a2, b2v, acc[2][2]);                            \
            acc[3][2] = MFMA16(a3, b2v, acc[3][2]);                            \
        }                                                                      \
    }

    G2CHUNK(0) G2CHUNK(1) G2CHUNK(2) G2CHUNK(3) G2CHUNK(4)
    G2CHUNK(5) G2CHUNK(6) G2CHUNK(7) G2CHUNK(8) G2CHUNK(9)

    asm volatile("s_waitcnt lgkmcnt(0)" ::: "memory");
    BARRIER();  // h1 reads done before h2 overwrite

    // ---------------- h2 = relu(C2+b2) -> hbuf -----------------------------
    HSTORE(0, b2)
    HSTORE(1, b2)
    if (t3) HSTORE(2, b2)
    asm volatile("s_waitcnt lgkmcnt(0)" ::: "memory");
    BARRIER();  // h2 visible

    // ---------------- GEMM3: waves 0-3 (mt=w); W3f frags from global -------
    if (w < 4) {
        f32x4 acc3 = (f32x4){0.f, 0.f, 0.f, 0.f};
#pragma unroll
        for (int kc3 = 0; kc3 < 10; ++kc3)
            acc3 = MFMA16(hbuf[(kc3 * 4 + w) * 64 + l], W3f[kc3 * 64 + l], acc3);
        if (l15 < 10) {
            float bias = b3[l15];
#pragma unroll
            for (int r = 0; r < 4; ++r)
                out[(size_t)(r0 + w * 16 + q * 4 + r) * 10 + l15] = acc3[r] + bias;
        }
    }
}

// ---------------------------------------------------------------------------
extern "C" void kernel_launch(void* const* d_in, const int* in_sizes, int n_in,
                              void* d_out, int out_size, void* d_ws, size_t ws_size,
                              hipStream_t stream) {
    const float* x      = (const float*)d_in[0];
    const float* conv_w = (const float*)d_in[1];
    const float* W1     = (const float*)d_in[2];
    const float* b1     = (const float*)d_in[3];
    const float* W2     = (const float*)d_in[4];
    const float* b2     = (const float*)d_in[5];
    const float* W3     = (const float*)d_in[6];
    const float* b3     = (const float*)d_in[7];
    float* out = (float*)d_out;

    char* ws = (char*)d_ws;
    bf16_t* W1f = (bf16_t*)(ws);
    bf16_t* W2f = (bf16_t*)(ws + (size_t)W1F_ELEMS * 2);
    bf16_t* W3f = (bf16_t*)(ws + (size_t)(W1F_ELEMS + W2F_ELEMS) * 2);
    if (ws_size < (size_t)(W1F_ELEMS + W2F_ELEMS + W3F_ELEMS) * 2) return;

    int prep_total = 800 * 320 + 320 * 320 + 320 * 16;  // 363520
    prep_weights<<<(prep_total + 255) / 256, 256, 0, stream>>>(
        conv_w, W1, W2, W3, W1f, W2f, W3f);

    fused_mlp<<<32768 / 64, 512, 0, stream>>>(
        x, b1, b2, b3, (const bf16x8*)W1f, (const bf16x8*)W2f,
        (const bf16x8*)W3f, out);
}

// Round 8
// 185.445 us; speedup vs baseline: 1.0174x; 1.0174x over previous
//
#include <hip/hip_runtime.h>

// ---------------------------------------------------------------------------
// DigitConvolutionalModel: x(32768,784) -> conv3x3(valid) -> 676
//   -> relu(@W1(676,300)+b1) -> relu(@W2(300,300)+b2) -> @W3(300,10)+b3
//
// R14 = R12 (all-async GEMM1 + counted waits -- verified 181.2us) with the
// wave decomposition changed 8x(4m x 3|2n) -> 4x(4m x 5n):
//  - A-tile LDS re-read per CU halves (8 -> 4 waves read the same band);
//    GEMM1 LDS floor ~22 -> ~13us. Per-wave MFMA density doubles (20/chunk).
//  - Uniform 5 n-tiles/wave: t3 divergence gone.
//  - acc[4][5] = 80 VGPR -> __launch_bounds__(256,2) (cap 256, no spill;
//    R13's spill was the 128-cap). Occupancy LDS-bound: 72KB -> 2 blocks/CU
//    = 8 waves/CU (reads ~25% -- expected).
//  - vmcnt literals re-derived: STAGE_B=5 ops, STAGE_BAND=4 (full) / 2
//    (band-12): VMW(4) even chunks, VMW(0) odd, VMW(2) at band-12 edge.
//  - B path / x f32 staging + XOR swizzle / tail / prep: R12 verbatim.
//  - Tripwires: WRITE_SIZE ~1.3MB (R13 spilled 10.5MB), FETCH ~55MB.
// ---------------------------------------------------------------------------

typedef __bf16 bf16_t;
typedef __bf16 bf16x8 __attribute__((ext_vector_type(8)));
typedef float  f32x4  __attribute__((ext_vector_type(4)));

#define MFMA16(a, b, c) __builtin_amdgcn_mfma_f32_16x16x32_bf16((a), (b), (c), 0, 0, 0)

#define W1F_ELEMS (25 * 20 * 64 * 8)  // 256000  (K=800, N=320)
#define W2F_ELEMS (10 * 20 * 64 * 8)  // 102400  (K=320, N=320)
#define W3F_ELEMS (10 * 1 * 64 * 8)   // 5120    (K=320, N=16)

#define XSLOT 16384   // one x band: 64 rows x 256B (64 f32 cols)
#define XBASE 40960   // Bbuf = 2 * 1280 frags * 16B

// ---------------------------------------------------------------------------
__global__ void prep_weights(const float* __restrict__ conv_w,
                             const float* __restrict__ W1,
                             const float* __restrict__ W2,
                             const float* __restrict__ W3,
                             bf16_t* __restrict__ W1f,
                             bf16_t* __restrict__ W2f,
                             bf16_t* __restrict__ W3f) {
    int idx = blockIdx.x * 256 + threadIdx.x;
    if (idx < 800 * 320) {
        int k = idx / 320;
        int n = idx - k * 320;
        float v = 0.0f;
        if (k < 784 && n < 300) {
            int py = k / 28;
            int px = k - py * 28;
#pragma unroll
            for (int ky = 0; ky < 3; ++ky) {
                int oy = py - ky;
                if (oy < 0 || oy > 25) continue;
#pragma unroll
                for (int kx = 0; kx < 3; ++kx) {
                    int ox = px - kx;
                    if (ox < 0 || ox > 25) continue;
                    v += conv_w[ky * 3 + kx] * W1[(oy * 26 + ox) * 300 + n];
                }
            }
        }
        int kc = k >> 5, quad = (k >> 3) & 3, j = k & 7;
        int nt = n >> 4, nin = n & 15;
        W1f[(((kc * 20 + nt) * 64 + quad * 16 + nin) << 3) + j] = (bf16_t)v;
    } else if (idx < 800 * 320 + 320 * 320) {
        int i2 = idx - 800 * 320;
        int k = i2 / 320;
        int n = i2 - k * 320;
        float v = (k < 300 && n < 300) ? W2[k * 300 + n] : 0.0f;
        int kc = k >> 5, quad = (k >> 3) & 3, j = k & 7;
        int nt = n >> 4, nin = n & 15;
        W2f[(((kc * 20 + nt) * 64 + quad * 16 + nin) << 3) + j] = (bf16_t)v;
    } else if (idx < 800 * 320 + 320 * 320 + 320 * 16) {
        int i3 = idx - (800 * 320 + 320 * 320);
        int k = i3 / 16;
        int n = i3 - k * 16;
        float v = (k < 300 && n < 10) ? W3[k * 10 + n] : 0.0f;
        int kc = k >> 5, quad = (k >> 3) & 3, j = k & 7;
        W3f[(((kc * 64) + quad * 16 + n) << 3) + j] = (bf16_t)v;
    }
}

// async global -> LDS, 16B/lane; LDS base wave-uniform, global addr per-lane.
__device__ __forceinline__ void stage16(const void* g, void* l) {
    __builtin_amdgcn_global_load_lds(
        (const __attribute__((address_space(1))) void*)g,
        (__attribute__((address_space(3))) void*)l, 16, 0, 0);
}

// ---------------------------------------------------------------------------
// Fused kernel. Block = 64 rows, 256 thr (4 waves). Wave w: 4 m-tiles x
// 5 n-tiles [w*5, w*5+5). B1 chunks LDS-dbuf'd; x f32 bands LDS ring-2.
// ---------------------------------------------------------------------------
__global__ __launch_bounds__(256, 2) void fused_mlp(
    const float* __restrict__ x, const float* __restrict__ b1,
    const float* __restrict__ b2, const float* __restrict__ b3,
    const bf16x8* __restrict__ W1f, const bf16x8* __restrict__ W2f,
    const bf16x8* __restrict__ W3f, float* __restrict__ out) {
    __shared__ __align__(16) unsigned char smem[XBASE + 2 * XSLOT];  // 72 KB
    bf16x8* Bb   = (bf16x8*)smem;  // [2][1280] B1 chunk dbuf
    bf16x8* hbuf = (bf16x8*)smem;  // 40 KB overlay after G1
    bf16_t* hb   = (bf16_t*)smem;

    const int tid = threadIdx.x;
    const int w   = tid >> 6;   // 0..3
    const int l   = tid & 63;
    const int q   = l >> 4;
    const int l15 = l & 15;
    const int r0  = blockIdx.x * 64;

    const int nt0 = w * 5;  // n-tiles [nt0, nt0+5)

    f32x4 acc[4][5];
#pragma unroll
    for (int m = 0; m < 4; ++m)
#pragma unroll
        for (int j = 0; j < 5; ++j) acc[m][j] = (f32x4){0.f, 0.f, 0.f, 0.f};

    // ---- B1 chunk staging: 20 groups of 64 frags; 5 groups/wave ----------
#define STAGE_B(KC, BUF)                                                       \
    {                                                                          \
        const bf16x8* ws_ = W1f + (size_t)(KC)*1280 + l;                       \
        bf16x8* wd_ = Bb + (BUF)*1280;                                         \
        stage16(ws_ + w * 64, wd_ + w * 64);                                   \
        stage16(ws_ + (w + 4) * 64, wd_ + (w + 4) * 64);                       \
        stage16(ws_ + (w + 8) * 64, wd_ + (w + 8) * 64);                       \
        stage16(ws_ + (w + 12) * 64, wd_ + (w + 12) * 64);                     \
        stage16(ws_ + (w + 16) * 64, wd_ + (w + 16) * 64);                     \
    }

    // ---- x band staging (R12-verified pattern, 4-wave row split) ---------
    // bands 0..11: 64 f32 cols, 4 issues/wave (16 rows); band 12: 32 cols,
    // 2 issues/wave. Source-side XOR swizzle (unit ^= row&7), linear dest.
    // Band-12 pad units (cols>=784) clamp to col 0: finite x zero W1f = 0.
#define STAGE_BAND(BAND)                                                       \
    {                                                                          \
        unsigned char* slot_ = smem + XBASE + ((BAND)&1) * XSLOT;              \
        if ((BAND) < 12) {                                                     \
            _Pragma("unroll")                                                  \
            for (int i_ = 0; i_ < 4; ++i_) {                                   \
                int row_ = w * 16 + i_ * 4 + (l >> 4);                         \
                int u_   = (l & 15) ^ (row_ & 7);                              \
                stage16(x + (size_t)(r0 + row_) * 784 + (BAND)*64 + u_ * 4,    \
                        slot_ + w * 4096 + i_ * 1024);                         \
            }                                                                  \
        } else {                                                               \
            _Pragma("unroll")                                                  \
            for (int i_ = 0; i_ < 2; ++i_) {                                   \
                int row_ = w * 16 + i_ * 8 + (l >> 3);                         \
                int u_   = (l & 7) ^ (row_ & 7);                               \
                const float* src_ = x + (size_t)(r0 + row_) * 784 +            \
                                    ((u_ < 4) ? (768 + u_ * 4) : 0);           \
                stage16(src_, slot_ + w * 2048 + i_ * 1024);                   \
            }                                                                  \
        }                                                                      \
    }

    // ---- A fragment: 2x ds_read_b128 f32 (swizzled) + cvt to bf16x8 ------
#define AFRAG(DST, SLOT, RS, KCL, MT)                                          \
    {                                                                          \
        int row_ = (MT)*16 + l15;                                              \
        int r7_  = row_ & 7;                                                   \
        float4 fa_ = *(const float4*)((SLOT) + row_ * (RS) +                   \
                     ((((KCL)*8 + q * 2 + 0) ^ r7_) << 4));                    \
        float4 fb_ = *(const float4*)((SLOT) + row_ * (RS) +                   \
                     ((((KCL)*8 + q * 2 + 1) ^ r7_) << 4));                    \
        bf16x8 t_;                                                             \
        t_[0] = (bf16_t)fa_.x; t_[1] = (bf16_t)fa_.y;                          \
        t_[2] = (bf16_t)fa_.z; t_[3] = (bf16_t)fa_.w;                          \
        t_[4] = (bf16_t)fb_.x; t_[5] = (bf16_t)fb_.y;                          \
        t_[6] = (bf16_t)fb_.z; t_[7] = (bf16_t)fb_.w;                          \
        DST = t_;                                                              \
    }

    // ---- one K=32 chunk: 4 m-tiles x 5 n-tiles, 20 MFMA, uniform ---------
#define G1CHUNK(SLOT, RS, KCL, BUF)                                            \
    {                                                                          \
        bf16x8 a0, a1, a2, a3;                                                 \
        AFRAG(a0, SLOT, RS, KCL, 0) AFRAG(a1, SLOT, RS, KCL, 1)                \
        AFRAG(a2, SLOT, RS, KCL, 2) AFRAG(a3, SLOT, RS, KCL, 3)                \
        const bf16x8* bb_ = Bb + (BUF)*1280 + nt0 * 64 + l;                    \
        bf16x8 b0 = bb_[0], b1v = bb_[64], b2v = bb_[128];                     \
        bf16x8 b3v = bb_[192], b4v = bb_[256];                                 \
        acc[0][0] = MFMA16(a0, b0, acc[0][0]);                                 \
        acc[1][0] = MFMA16(a1, b0, acc[1][0]);                                 \
        acc[2][0] = MFMA16(a2, b0, acc[2][0]);                                 \
        acc[3][0] = MFMA16(a3, b0, acc[3][0]);                                 \
        acc[0][1] = MFMA16(a0, b1v, acc[0][1]);                                \
        acc[1][1] = MFMA16(a1, b1v, acc[1][1]);                                \
        acc[2][1] = MFMA16(a2, b1v, acc[2][1]);                                \
        acc[3][1] = MFMA16(a3, b1v, acc[3][1]);                                \
        acc[0][2] = MFMA16(a0, b2v, acc[0][2]);                                \
        acc[1][2] = MFMA16(a1, b2v, acc[1][2]);                                \
        acc[2][2] = MFMA16(a2, b2v, acc[2][2]);                                \
        acc[3][2] = MFMA16(a3, b2v, acc[3][2]);                                \
        acc[0][3] = MFMA16(a0, b3v, acc[0][3]);                                \
        acc[1][3] = MFMA16(a1, b3v, acc[1][3]);                                \
        acc[2][3] = MFMA16(a2, b3v, acc[2][3]);                                \
        acc[3][3] = MFMA16(a3, b3v, acc[3][3]);                                \
        acc[0][4] = MFMA16(a0, b4v, acc[0][4]);                                \
        acc[1][4] = MFMA16(a1, b4v, acc[1][4]);                                \
        acc[2][4] = MFMA16(a2, b4v, acc[2][4]);                                \
        acc[3][4] = MFMA16(a3, b4v, acc[3][4]);                                \
    }

#define VMW(N) asm volatile("s_waitcnt vmcnt(" #N ") lgkmcnt(0)" ::: "memory")
#define BARRIER()                         \
    __builtin_amdgcn_s_barrier();         \
    __builtin_amdgcn_sched_barrier(0)

    // ---------------- GEMM1: 25 chunks (bands of 2), all-LDS operands ------
    // prologue: B_0 + X_0; cold-start drain.
    STAGE_B(0, 0)
    STAGE_BAND(0)
    VMW(0);
    BARRIER();

    for (int b = 0; b <= 10; ++b) {
        unsigned char* xs = smem + XBASE + (b & 1) * XSLOT;
        const int k0 = 2 * b;
        // even chunk k0: stage B_{k0+1} then X_{b+1}; compute; X stays in flight
        STAGE_B(k0 + 1, (k0 + 1) & 1)
        STAGE_BAND(b + 1)
        G1CHUNK(xs, 256, 0, k0 & 1)
        VMW(4);
        BARRIER();
        // odd chunk k0+1: stage B_{k0+2}; compute; drain
        STAGE_B(k0 + 2, (k0 + 2) & 1)
        G1CHUNK(xs, 256, 1, (k0 + 1) & 1)
        VMW(0);
        BARRIER();
    }
    // band 11 (chunks 22, 23); stages band 12 (2 ops -> VMW(2))
    {
        unsigned char* xs = smem + XBASE + XSLOT;  // slot 1
        STAGE_B(23, 1)
        STAGE_BAND(12)
        G1CHUNK(xs, 256, 0, 0)
        VMW(2);
        BARRIER();
        STAGE_B(24, 0)
        G1CHUNK(xs, 256, 1, 1)
        VMW(0);
        BARRIER();
    }
    // band 12 (chunk 24, 32 cols, row stride 128; slot 0)
    {
        unsigned char* xs = smem + XBASE;
        G1CHUNK(xs, 128, 0, 0)
        asm volatile("s_waitcnt lgkmcnt(0)" ::: "memory");
        BARRIER();  // all Bbuf/x reads done before hbuf overlay
    }

    // ---------------- h1 = relu(C1+b1) -> hbuf (A-frag order) --------------
#define HSTORE(J, BIAS)                                                        \
    {                                                                          \
        int n = (nt0 + (J)) * 16 + l15;                                        \
        float bias = (n < 300) ? (BIAS)[n] : 0.0f;                             \
        int kh = n >> 5, quad = (n >> 3) & 3, jj = n & 7;                      \
        _Pragma("unroll")                                                      \
        for (int mt = 0; mt < 4; ++mt)                                         \
            _Pragma("unroll")                                                  \
            for (int r = 0; r < 4; ++r) {                                      \
                float v = acc[mt][(J)][r] + bias;                              \
                v = v > 0.f ? v : 0.f;                                         \
                hb[(((kh * 4 + mt) * 64 + quad * 16 + q * 4 + r) << 3) + jj] = \
                    (bf16_t)v;                                                 \
            }                                                                  \
    }

    HSTORE(0, b1) HSTORE(1, b1) HSTORE(2, b1) HSTORE(3, b1) HSTORE(4, b1)
    asm volatile("s_waitcnt lgkmcnt(0)" ::: "memory");
    BARRIER();  // h1 visible

    // ---------------- GEMM2: barrier-free; W2f frags from global (L2) ------
#pragma unroll
    for (int m = 0; m < 4; ++m)
#pragma unroll
        for (int j = 0; j < 5; ++j) acc[m][j] = (f32x4){0.f, 0.f, 0.f, 0.f};

    const bf16x8* bB2 = W2f + nt0 * 64 + l;

#define G2CHUNK(KC2)                                                           \
    {                                                                          \
        bf16x8 a0 = hbuf[((KC2)*4 + 0) * 64 + l];                              \
        bf16x8 a1 = hbuf[((KC2)*4 + 1) * 64 + l];                              \
        bf16x8 a2 = hbuf[((KC2)*4 + 2) * 64 + l];                              \
        bf16x8 a3 = hbuf[((KC2)*4 + 3) * 64 + l];                              \
        const bf16x8* bp = bB2 + (KC2)*1280;                                   \
        bf16x8 b0 = bp[0], b1v = bp[64], b2v = bp[128];                        \
        bf16x8 b3v = bp[192], b4v = bp[256];                                   \
        acc[0][0] = MFMA16(a0, b0, acc[0][0]);                                 \
        acc[1][0] = MFMA16(a1, b0, acc[1][0]);                                 \
        acc[2][0] = MFMA16(a2, b0, acc[2][0]);                                 \
        acc[3][0] = MFMA16(a3, b0, acc[3][0]);                                 \
        acc[0][1] = MFMA16(a0, b1v, acc[0][1]);                                \
        acc[1][1] = MFMA16(a1, b1v, acc[1][1]);                                \
        acc[2][1] = MFMA16(a2, b1v, acc[2][1]);                                \
        acc[3][1] = MFMA16(a3, b1v, acc[3][1]);                                \
        acc[0][2] = MFMA16(a0, b2v, acc[0][2]);                                \
        acc[1][2] = MFMA16(a1, b2v, acc[1][2]);                                \
        acc[2][2] = MFMA16(a2, b2v, acc[2][2]);                                \
        acc[3][2] = MFMA16(a3, b2v, acc[3][2]);                                \
        acc[0][3] = MFMA16(a0, b3v, acc[0][3]);                                \
        acc[1][3] = MFMA16(a1, b3v, acc[1][3]);                                \
        acc[2][3] = MFMA16(a2, b3v, acc[2][3]);                                \
        acc[3][3] = MFMA16(a3, b3v, acc[3][3]);                                \
        acc[0][4] = MFMA16(a0, b4v, acc[0][4]);                                \
        acc[1][4] = MFMA16(a1, b4v, acc[1][4]);                                \
        acc[2][4] = MFMA16(a2, b4v, acc[2][4]);                                \
        acc[3][4] = MFMA16(a3, b4v, acc[3][4]);                                \
    }

    G2CHUNK(0) G2CHUNK(1) G2CHUNK(2) G2CHUNK(3) G2CHUNK(4)
    G2CHUNK(5) G2CHUNK(6) G2CHUNK(7) G2CHUNK(8) G2CHUNK(9)

    asm volatile("s_waitcnt lgkmcnt(0)" ::: "memory");
    BARRIER();  // h1 reads done before h2 overwrite

    // ---------------- h2 = relu(C2+b2) -> hbuf -----------------------------
    HSTORE(0, b2) HSTORE(1, b2) HSTORE(2, b2) HSTORE(3, b2) HSTORE(4, b2)
    asm volatile("s_waitcnt lgkmcnt(0)" ::: "memory");
    BARRIER();  // h2 visible

    // ---------------- GEMM3: all 4 waves (mt=w); W3f frags from global -----
    {
        f32x4 acc3 = (f32x4){0.f, 0.f, 0.f, 0.f};
#pragma unroll
        for (int kc3 = 0; kc3 < 10; ++kc3)
            acc3 = MFMA16(hbuf[(kc3 * 4 + w) * 64 + l], W3f[kc3 * 64 + l], acc3);
        if (l15 < 10) {
            float bias = b3[l15];
#pragma unroll
            for (int r = 0; r < 4; ++r)
                out[(size_t)(r0 + w * 16 + q * 4 + r) * 10 + l15] = acc3[r] + bias;
        }
    }
}

// ---------------------------------------------------------------------------
extern "C" void kernel_launch(void* const* d_in, const int* in_sizes, int n_in,
                              void* d_out, int out_size, void* d_ws, size_t ws_size,
                              hipStream_t stream) {
    const float* x      = (const float*)d_in[0];
    const float* conv_w = (const float*)d_in[1];
    const float* W1     = (const float*)d_in[2];
    const float* b1     = (const float*)d_in[3];
    const float* W2     = (const float*)d_in[4];
    const float* b2     = (const float*)d_in[5];
    const float* W3     = (const float*)d_in[6];
    const float* b3     = (const float*)d_in[7];
    float* out = (float*)d_out;

    char* ws = (char*)d_ws;
    bf16_t* W1f = (bf16_t*)(ws);
    bf16_t* W2f = (bf16_t*)(ws + (size_t)W1F_ELEMS * 2);
    bf16_t* W3f = (bf16_t*)(ws + (size_t)(W1F_ELEMS + W2F_ELEMS) * 2);
    if (ws_size < (size_t)(W1F_ELEMS + W2F_ELEMS + W3F_ELEMS) * 2) return;

    int prep_total = 800 * 320 + 320 * 320 + 320 * 16;  // 363520
    prep_weights<<<(prep_total + 255) / 256, 256, 0, stream>>>(
        conv_w, W1, W2, W3, W1f, W2f, W3f);

    fused_mlp<<<32768 / 64, 256, 0, stream>>>(
        x, b1, b2, b3, (const bf16x8*)W1f, (const bf16x8*)W2f,
        (const bf16x8*)W3f, out);
}